// Round 8
// baseline (5368.523 us; speedup 1.0000x reference)
//
#include <hip/hip_runtime.h>
#include <math.h>
#include <utility>

#define TB 1024   // batch
#define HH 100    // hidden
#define GG 300    // 3*H gate rows

// ---------------------------------------------------------------------------
// NUMERICS ARE FROZEN — DO NOT TOUCH.
// History: R1 (__expf), R5 (naive exp2), R6 (1-ulp Cody-Waite expm1, fully
// cancellation-free) ALL flipped the same decoder argmax site (absmax=14).
// Only the ocml expf/tanhf profile (R2/R3/R7) lands on the reference side of
// a knife-edge logit near-tie. Rounding-profile luck, not accuracy class —
// the transcendentals AND the GEMV/gate expression DAG must stay bit-
// identical. Perf work must be value-neutral (BB/grid/schedule only).
// ---------------------------------------------------------------------------
__device__ __forceinline__ float sigmoidf_(float x) {
    return 1.0f / (1.0f + expf(-x));
}
__device__ __forceinline__ float tanhf_(float x) {
    return tanhf(x);
}

// ---------------------------------------------------------------------------
// Compile-time-constant-index load + VALUE-SEMANTICS register pin (R7 WIN:
// VGPR 84->128, VALUBusy 28->55%, 5894->4799us. pin_val makes each weight an
// asm RESULT — non-rematerializable, non-sinkable — forcing VGPR residency
// up to the allocator's cap; the rest spills to scratch (visible as the
// FETCH_SIZE 32->105MB delta, L2-resident).
// ---------------------------------------------------------------------------
template<size_t... Is>
__device__ __forceinline__ void ldN(std::index_sequence<Is...>,
                                    float* __restrict__ dst,
                                    const float* __restrict__ src) {
    ((dst[Is] = src[Is]), ...);
}
__device__ __forceinline__ float pin_val(float v) {
    asm volatile("" : "+v"(v));
    return v;
}
template<size_t... Is>
__device__ __forceinline__ void pinN(std::index_sequence<Is...>, float* w) {
    ((w[Is] = pin_val(w[Is])), ...);
}

template<int KK, int BB, int LD>
__device__ __forceinline__ void fma_step(const float* __restrict__ w,
                                         const float (*xs)[LD],
                                         float* __restrict__ acc) {
    #pragma unroll
    for (int b = 0; b < BB; ++b) {
        const float4 xv = *reinterpret_cast<const float4*>(&xs[b][KK]);
        acc[b] += w[KK]     * xv.x + w[KK + 1] * xv.y
                + w[KK + 2] * xv.z + w[KK + 3] * xv.w;
    }
}
template<int BB, int LD, size_t... Is>
__device__ __forceinline__ void gemv4(std::index_sequence<Is...>,
                                      const float* __restrict__ w,
                                      const float (*xs)[LD],
                                      float* __restrict__ acc) {
    (fma_step<(int)(Is * 4), BB, LD>(w, xs, acc), ...);
}

// Persistent GRU layer kernel.
// R8: BB=2, grid=512 (2 blocks/CU, 10 waves/CU -> 3/3/2/2 per SIMD).
// R7 ran 1 block/CU of 5 waves -> 2/1/1/1: issue ceiling 62.5% (measured
// VALUBusy 55%). 10 waves/CU raises the balance ceiling to ~83% and hides
// scratch-reload/LDS latency at 2.5 waves/SIMD. Value-neutral vs R7.
// Thread j in [0,300): gate g=j/100 (0=r,1=z,2=n), unit i=j%100.
template<int K, bool EMB, bool WRITE_SEQ>
__global__ __launch_bounds__(320, 1)
void gru_kernel(const float* __restrict__ xin,   // [T,B,K] (if !EMB)
                const int*   __restrict__ tgt,   // [T,B]   (if EMB)
                const float* __restrict__ emb,   // [64,26] (if EMB)
                const float* __restrict__ Wih,   // [300,K]
                const float* __restrict__ Whh,   // [300,100]
                const float* __restrict__ bih,
                const float* __restrict__ bhh,
                const float* __restrict__ h_init,// [B,100] or null -> zeros
                float* __restrict__ seq_out,     // [T,B,100] (if WRITE_SEQ)
                float* __restrict__ h_last,      // [B,100] or null
                int T)
{
    constexpr int KP = (K + 3) & ~3;   // 28 or 100
    constexpr int BB = 2;
    static_assert(KP % 4 == 0, "");

    const int tid = threadIdx.x;
    const int bb0 = blockIdx.x * BB;
    const int j   = tid;
    const int g   = j / 100;
    const int i   = j % 100;

    __shared__ __align__(16) float h_s[BB][HH];
    __shared__ __align__(16) float x_s[BB][KP];
    __shared__ float r_s[BB][HH];
    __shared__ float z_s[BB][HH];
    __shared__ float emb_s[EMB ? 64 : 1][EMB ? 28 : 4];
    __shared__ int   tgt_s[BB];

    // ---- weights into registers (one-time, unconditional w/ clamped row) ----
    const int jj = (j < GG) ? j : 0;
    float wih[KP];
    float whh[HH];
    ldN(std::make_index_sequence<K>{},  wih, Wih + (long)jj * K);
    #pragma unroll
    for (int k = K; k < KP; ++k) wih[k] = 0.f;
    ldN(std::make_index_sequence<HH>{}, whh, Whh + (long)jj * HH);
    float bi = bih[jj];
    float bh = bhh[jj];
    pinN(std::make_index_sequence<KP>{}, wih);
    pinN(std::make_index_sequence<HH>{}, whh);
    bi = pin_val(bi);
    bh = pin_val(bh);

    // ---- init h ----
    for (int idx = tid; idx < BB * HH; idx += 320) {
        int b = idx / HH, k = idx % HH;
        h_s[b][k] = h_init ? h_init[(bb0 + b) * HH + k] : 0.f;
    }
    // ---- init x_s for t=0 ----
    if constexpr (EMB) {
        for (int idx = tid; idx < 64 * 28; idx += 320) {
            int d = idx / 28, k = idx % 28;
            emb_s[d][k] = (k < 26) ? emb[d * 26 + k] : 0.f;
        }
        __syncthreads();
        for (int idx = tid; idx < BB * KP; idx += 320) {
            int b = idx / KP, k = idx % KP;
            int t0 = tgt[bb0 + b];
            x_s[b][k] = emb_s[t0][k];          // pads are 0 via emb_s
        }
    } else {
        for (int idx = tid; idx < BB * KP; idx += 320) {
            int b = idx / KP, k = idx % KP;
            x_s[b][k] = (k < K) ? xin[(bb0 + b) * K + k] : 0.f;
        }
    }
    __syncthreads();

    // ---- time loop ----
    for (int t = 0; t < T; ++t) {
        const bool has_next = (t + 1 < T);

        // prefetch next step's input into regs (hidden under FMA loop)
        float px[2] = {0.f, 0.f};
        int   ptg   = 0;
        if constexpr (!EMB) {
            if (has_next && !(tid >= 200 && tid < 300)) {
                int stid = (tid < 200) ? tid : tid - 100;   // 0..219
                #pragma unroll
                for (int it = 0; it < 2; ++it) {
                    int idx = stid + it * 220;
                    if (idx < BB * K)
                        px[it] = xin[((t + 1) * TB + bb0 + idx / K) * K + idx % K];
                }
            }
        } else {
            if (has_next && tid < BB) ptg = tgt[(t + 1) * TB + bb0 + tid];
        }

        // main GEMV: acc_i = Wih[j,:].x + bi ; acc_h = Whh[j,:].h + bh
        float acc_i[BB], acc_h[BB];
        #pragma unroll
        for (int b = 0; b < BB; ++b) { acc_i[b] = bi; acc_h[b] = bh; }

        gemv4<BB, KP>(std::make_index_sequence<KP / 4>{}, wih, x_s, acc_i);
        gemv4<BB, HH>(std::make_index_sequence<HH / 4>{}, whh, h_s, acc_h);

        // r / z gates -> LDS
        if (j < 200) {
            #pragma unroll
            for (int b = 0; b < BB; ++b) {
                float v = sigmoidf_(acc_i[b] + acc_h[b]);
                if (g == 0) r_s[b][i] = v;
                else        z_s[b][i] = v;
            }
        }
        __syncthreads();   // B1: gates visible

        if (j >= 200 && j < 300) {
            // n gate + state update (100 threads)
            #pragma unroll
            for (int b = 0; b < BB; ++b) {
                float n  = tanhf_(acc_i[b] + r_s[b][i] * acc_h[b]);
                float z  = z_s[b][i];
                float hn = (1.f - z) * n + z * h_s[b][i];
                h_s[b][i] = hn;
                if (WRITE_SEQ)
                    seq_out[((long)t * TB + bb0 + b) * HH + i] = hn;
            }
        } else if constexpr (!EMB) {
            if (has_next) {
                int stid = (tid < 200) ? tid : tid - 100;
                #pragma unroll
                for (int it = 0; it < 2; ++it) {
                    int idx = stid + it * 220;
                    if (idx < BB * K) x_s[idx / K][idx % K] = px[it];
                }
            }
        }
        if constexpr (EMB) {
            if (has_next && tid < BB) tgt_s[tid] = ptg;
            __syncthreads();   // B2: tgt_s visible
            if (has_next && tid < BB * KP) {
                int b = tid / KP, k = tid % KP;
                x_s[b][k] = emb_s[tgt_s[b]][k];
            }
        }
        __syncthreads();       // step barrier: h_s and x_s ready
    }

    if (h_last != nullptr && j >= 200 && j < 300) {
        #pragma unroll
        for (int b = 0; b < BB; ++b)
            h_last[(bb0 + b) * HH + i] = h_s[b][i];
    }
}

// Final linear + argmax + target_cal.
// block = 256 = 4 slots x 64 lanes (lane = output class d, wave = one (p,b) slot)
__global__ __launch_bounds__(256)
void final_kernel(const float* __restrict__ d1,
                  const float* __restrict__ linW,   // [64,100]
                  const float* __restrict__ linb,   // [64]
                  const int*   __restrict__ tgt,    // [80,1024]
                  float* __restrict__ out0,         // [79*1024,64] logits
                  float* __restrict__ out1,         // [79*1024] target_cal
                  float* __restrict__ out2)         // [79*1024] argmax
{
    __shared__ float WT[HH][64];     // WT[k][d]
    __shared__ __align__(16) float row[4][HH];

    const int tid = threadIdx.x;
    for (int idx = tid; idx < 64 * HH; idx += 256) {
        int d = idx / HH, k = idx % HH;
        WT[k][d] = linW[idx];
    }
    const int s    = tid >> 6;
    const int d    = tid & 63;
    const int slot = blockIdx.x * 4 + s;     // < 79*1024
    const int p    = slot >> 10;
    const int b    = slot & 1023;
    const float* drow = &d1[(long)(p * TB + b) * HH];
    __syncthreads();
    if (d < 50) {
        float2 v = *reinterpret_cast<const float2*>(&drow[2 * d]);
        row[s][2 * d]     = v.x;
        row[s][2 * d + 1] = v.y;
    }
    __syncthreads();

    float acc = linb[d];
    #pragma unroll
    for (int k = 0; k < HH; ++k)
        acc += row[s][k] * WT[k][d];

    out0[(long)slot * 64 + d] = acc;

    // argmax over 64 lanes, first-occurrence tie-break (min index among maxima)
    float mv = acc;
    int   mi = d;
    #pragma unroll
    for (int off = 32; off >= 1; off >>= 1) {
        float ov = __shfl_xor(mv, off, 64);
        int   oi = __shfl_xor(mi, off, 64);
        if (ov > mv || (ov == mv && oi < mi)) { mv = ov; mi = oi; }
    }
    if (d == 0) out2[slot] = (float)mi;
    if (d == 1) out1[slot] = (float)tgt[(p + 1) * TB + b];
}

extern "C" void kernel_launch(void* const* d_in, const int* in_sizes, int n_in,
                              void* d_out, int out_size, void* d_ws, size_t ws_size,
                              hipStream_t stream)
{
    const float* x      = (const float*)d_in[0];
    const int*   target = (const int*)  d_in[1];
    const float* emb    = (const float*)d_in[2];
    const float* eWih0  = (const float*)d_in[3];
    const float* eWhh0  = (const float*)d_in[4];
    const float* ebih0  = (const float*)d_in[5];
    const float* ebhh0  = (const float*)d_in[6];
    const float* eWih1  = (const float*)d_in[7];
    const float* eWhh1  = (const float*)d_in[8];
    const float* ebih1  = (const float*)d_in[9];
    const float* ebhh1  = (const float*)d_in[10];
    const float* dWih0  = (const float*)d_in[11];
    const float* dWhh0  = (const float*)d_in[12];
    const float* dbih0  = (const float*)d_in[13];
    const float* dbhh0  = (const float*)d_in[14];
    const float* dWih1  = (const float*)d_in[15];
    const float* dWhh1  = (const float*)d_in[16];
    const float* dbih1  = (const float*)d_in[17];
    const float* dbhh1  = (const float*)d_in[18];
    const float* linW   = (const float*)d_in[19];
    const float* linb   = (const float*)d_in[20];

    // workspace layout (floats):
    //  [0, 102400)                       h_enc0
    //  [102400, 204800)                  h_enc1
    //  [204800, 204800+51.2M)            e0 during encoder
    //  same region reused for d0/d1 during decoder (e0 dead by then)
    float* ws     = (float*)d_ws;
    float* h_enc0 = ws;
    float* h_enc1 = ws + 102400;
    float* e0     = ws + 204800;                      // 500*1024*100
    float* d0     = ws + 204800;                      // aliases e0 (dead)
    float* d1_    = ws + 204800 + 80 * 1024 * 100;    // 80*1024*100

    dim3 grid(512), blk(320);   // BB=2 -> 512 blocks, 2 blocks/CU
    // encoder layer 0: raw x input (K=26), write e0 + h_enc0
    gru_kernel<26,  false, true ><<<grid, blk, 0, stream>>>(
        x, nullptr, nullptr, eWih0, eWhh0, ebih0, ebhh0, nullptr, e0, h_enc0, 500);
    // encoder layer 1: e0 input (K=100), only h_enc1 needed
    gru_kernel<100, false, false><<<grid, blk, 0, stream>>>(
        e0, nullptr, nullptr, eWih1, eWhh1, ebih1, ebhh1, nullptr, nullptr, h_enc1, 500);
    // decoder layer 0: embedding-gather input (K=26), h0 = h_enc0
    gru_kernel<26,  true,  true ><<<grid, blk, 0, stream>>>(
        nullptr, target, emb, dWih0, dWhh0, dbih0, dbhh0, h_enc0, d0, nullptr, 80);
    // decoder layer 1: d0 input (K=100), h0 = h_enc1, write d1
    gru_kernel<100, false, true ><<<grid, blk, 0, stream>>>(
        d0, nullptr, nullptr, dWih1, dWhh1, dbih1, dbhh1, h_enc1, d1_, nullptr, 80);

    float* out0 = (float*)d_out;
    float* out1 = out0 + (long)79 * 1024 * 64;
    float* out2 = out1 + 79 * 1024;
    final_kernel<<<dim3(20224), dim3(256), 0, stream>>>(d1_, linW, linb, target,
                                                        out0, out1, out2);
}

// Round 9
// 3592.266 us; speedup vs baseline: 1.4945x; 1.4945x over previous
//
#include <hip/hip_runtime.h>
#include <math.h>
#include <utility>

#define TB 1024   // batch
#define HH 100    // hidden
#define GG 300    // 3*H gate rows

// ---------------------------------------------------------------------------
// NUMERICS ARE FROZEN — DO NOT TOUCH.
// R1 (__expf), R5 (naive exp2), R6 (1-ulp Cody-Waite expm1) ALL flipped the
// same decoder argmax site (absmax=14). Only the ocml expf/tanhf profile
// (R2/R3/R7/R8) lands on the reference side of a knife-edge logit near-tie.
// The transcendentals AND the per-element GEMV/gate expression DAG (values,
// pairing, order) must stay bit-identical. Perf work must be value-neutral.
// ---------------------------------------------------------------------------
__device__ __forceinline__ float sigmoidf_(float x) {
    return 1.0f / (1.0f + expf(-x));
}
__device__ __forceinline__ float tanhf_(float x) {
    return tanhf(x);
}

// ---------------------------------------------------------------------------
// R8 post-mortem: two 320-thread blocks never co-reside on a CU (occupancy
// stayed 15%; dispatch time = two serialized half-work passes). Per-CU
// concurrency must come from ONE bigger block. Also VGPR demand (wih+whh =
// 200+ floats) overflowed the 128-reg grant -> ~100 floats/thread spilled.
// R9 design: 640-thread block = 2 teams x 300 rows (+40 pad), BT=2 batch per
// team; Whh (120KB) lives in LDS k-packed [k/4][row][4], SHARED by teams;
// wih stays in pinned VGPRs (<=100 floats; fits under the 168 cap from
// __launch_bounds__(640,3) -> no spill). Whh LDS reads are lane-stride-16B
// b128 = canonical conflict-free pattern. FP DAG bit-identical to R7.
// ---------------------------------------------------------------------------
template<size_t... Is>
__device__ __forceinline__ void ldN(std::index_sequence<Is...>,
                                    float* __restrict__ dst,
                                    const float* __restrict__ src) {
    ((dst[Is] = src[Is]), ...);
}
__device__ __forceinline__ float pin_val(float v) {
    asm volatile("" : "+v"(v));
    return v;
}
template<size_t... Is>
__device__ __forceinline__ void pinN(std::index_sequence<Is...>, float* w) {
    ((w[Is] = pin_val(w[Is])), ...);
}

// acc_i: weights from per-thread registers (wih), x broadcast from LDS.
template<int KK, int BT, int LD>
__device__ __forceinline__ void fma_step(const float* __restrict__ w,
                                         const float (*xs)[LD],
                                         float* __restrict__ acc) {
    #pragma unroll
    for (int b = 0; b < BT; ++b) {
        const float4 xv = *reinterpret_cast<const float4*>(&xs[b][KK]);
        acc[b] += w[KK]     * xv.x + w[KK + 1] * xv.y
                + w[KK + 2] * xv.z + w[KK + 3] * xv.w;
    }
}
template<int BT, int LD, size_t... Is>
__device__ __forceinline__ void gemv4(std::index_sequence<Is...>,
                                      const float* __restrict__ w,
                                      const float (*xs)[LD],
                                      float* __restrict__ acc) {
    (fma_step<(int)(Is * 4), BT, LD>(w, xs, acc), ...);
}

// acc_h: weights from LDS k-packed [grp][row][4], h broadcast from LDS.
// Pairing/order identical to fma_step: wv.x==w[4g+0] pairs hv.x==h[4g+0], ...
template<int GRP, int BT>
__device__ __forceinline__ void fma_lds_step(const float* __restrict__ wl,
                                             int row,
                                             const float (*hs)[HH],
                                             float* __restrict__ acc) {
    const float4 wv = *reinterpret_cast<const float4*>(wl + (GRP * GG + row) * 4);
    #pragma unroll
    for (int b = 0; b < BT; ++b) {
        const float4 hv = *reinterpret_cast<const float4*>(&hs[b][GRP * 4]);
        acc[b] += wv.x * hv.x + wv.y * hv.y + wv.z * hv.z + wv.w * hv.w;
    }
}
template<int BT, size_t... Is>
__device__ __forceinline__ void gemv_lds(std::index_sequence<Is...>,
                                         const float* __restrict__ wl, int row,
                                         const float (*hs)[HH],
                                         float* __restrict__ acc) {
    (fma_lds_step<(int)Is, BT>(wl, row, hs, acc), ...);
}

// Persistent GRU layer kernel. grid=256 blocks, block=640 threads (10 waves).
// team = tid/320 (2 teams of 300 gate-rows + 20 pad), each team owns BT=2
// batch elements; whh shared in LDS. 10 waves/CU -> 3/3/2/2 per SIMD.
template<int K, bool EMB, bool WRITE_SEQ>
__global__ __launch_bounds__(640, 3)
void gru_kernel(const float* __restrict__ xin,   // [T,B,K] (if !EMB)
                const int*   __restrict__ tgt,   // [T,B]   (if EMB)
                const float* __restrict__ emb,   // [64,26] (if EMB)
                const float* __restrict__ Wih,   // [300,K]
                const float* __restrict__ Whh,   // [300,100]
                const float* __restrict__ bih,
                const float* __restrict__ bhh,
                const float* __restrict__ h_init,// [B,100] or null -> zeros
                float* __restrict__ seq_out,     // [T,B,100] (if WRITE_SEQ)
                float* __restrict__ h_last,      // [B,100] or null
                int T)
{
    constexpr int KP = (K + 3) & ~3;   // 28 or 100
    constexpr int BT = 2;              // batch per team
    constexpr int NT = 2;              // teams
    static_assert(KP % 4 == 0, "");

    const int tid  = threadIdx.x;
    const int team = tid / 320;
    const int tj   = tid % 320;        // row index within team (0..319)
    const int bb0  = blockIdx.x * (BT * NT) + team * BT;
    const int g    = tj / 100;
    const int i    = tj % 100;

    __shared__ __align__(16) float whh_l[(HH / 4) * GG * 4];  // 120000 B
    __shared__ __align__(16) float h_s[NT][BT][HH];
    __shared__ __align__(16) float x_s[NT][BT][KP];
    __shared__ float r_s[NT][BT][HH];
    __shared__ float z_s[NT][BT][HH];
    __shared__ float emb_s[EMB ? 64 : 1][EMB ? 28 : 4];
    __shared__ int   tgt_s[NT * BT];

    // ---- wih row into registers (one-time, unconditional w/ clamped row) ----
    const int jj = (tj < GG) ? tj : 0;
    float wih[KP];
    ldN(std::make_index_sequence<K>{}, wih, Wih + (long)jj * K);
    #pragma unroll
    for (int k = K; k < KP; ++k) wih[k] = 0.f;
    float bi = bih[jj];
    float bh = bhh[jj];
    pinN(std::make_index_sequence<KP>{}, wih);
    bi = pin_val(bi);
    bh = pin_val(bh);

    // ---- stage whh into LDS, k-packed: whh_l[(k/4)*GG + row][k%4] ----
    for (int idx = tid; idx < GG * HH; idx += 640) {
        int row = idx / HH, k = idx % HH;
        whh_l[((k >> 2) * GG + row) * 4 + (k & 3)] = Whh[row * HH + k];
    }

    // ---- init h (per team) ----
    for (int idx = tj; idx < BT * HH; idx += 320) {
        int b = idx / HH, k = idx % HH;
        h_s[team][b][k] = h_init ? h_init[(bb0 + b) * HH + k] : 0.f;
    }
    // ---- init x_s for t=0 ----
    if constexpr (EMB) {
        for (int idx = tid; idx < 64 * 28; idx += 640) {
            int d = idx / 28, k = idx % 28;
            emb_s[d][k] = (k < 26) ? emb[d * 26 + k] : 0.f;
        }
        __syncthreads();
        for (int idx = tj; idx < BT * KP; idx += 320) {
            int b = idx / KP, k = idx % KP;
            int t0 = tgt[bb0 + b];
            x_s[team][b][k] = emb_s[t0][k];    // pads are 0 via emb_s
        }
    } else {
        for (int idx = tj; idx < BT * KP; idx += 320) {
            int b = idx / KP, k = idx % KP;
            x_s[team][b][k] = (k < K) ? xin[(bb0 + b) * K + k] : 0.f;
        }
    }
    __syncthreads();   // whh_l, h_s, x_s ready

    // ---- time loop ----
    for (int t = 0; t < T; ++t) {
        const bool has_next = (t + 1 < T);

        // prefetch next step's input into regs (hidden under FMA loop)
        float px = 0.f;
        int   ptg = 0;
        if constexpr (!EMB) {
            if (has_next && !(tj >= 200 && tj < 300)) {
                int stid = (tj < 200) ? tj : tj - 100;   // 0..219
                if (stid < BT * K)
                    px = xin[((t + 1) * TB + bb0 + stid / K) * K + stid % K];
            }
        } else {
            if (has_next && tj < BT) ptg = tgt[(t + 1) * TB + bb0 + tj];
        }

        // main GEMV: acc_i = Wih[j,:].x + bi ; acc_h = Whh[j,:].h + bh
        float acc_i[BT], acc_h[BT];
        #pragma unroll
        for (int b = 0; b < BT; ++b) { acc_i[b] = bi; acc_h[b] = bh; }

        gemv4<BT, KP>(std::make_index_sequence<KP / 4>{}, wih, x_s[team], acc_i);
        gemv_lds<BT>(std::make_index_sequence<HH / 4>{}, whh_l, jj, h_s[team], acc_h);

        // r / z gates -> LDS
        if (tj < 200) {
            #pragma unroll
            for (int b = 0; b < BT; ++b) {
                float v = sigmoidf_(acc_i[b] + acc_h[b]);
                if (g == 0) r_s[team][b][i] = v;
                else        z_s[team][b][i] = v;
            }
        }
        __syncthreads();   // B1: gates visible

        if (tj >= 200 && tj < 300) {
            // n gate + state update (100 threads per team)
            #pragma unroll
            for (int b = 0; b < BT; ++b) {
                float n  = tanhf_(acc_i[b] + r_s[team][b][i] * acc_h[b]);
                float z  = z_s[team][b][i];
                float hn = (1.f - z) * n + z * h_s[team][b][i];
                h_s[team][b][i] = hn;
                if (WRITE_SEQ)
                    seq_out[((long)t * TB + bb0 + b) * HH + i] = hn;
            }
        } else if constexpr (!EMB) {
            if (has_next) {
                int stid = (tj < 200) ? tj : tj - 100;
                if (stid < BT * K) x_s[team][stid / K][stid % K] = px;
            }
        }
        if constexpr (EMB) {
            if (has_next && tj < BT) tgt_s[team * BT + tj] = ptg;
            __syncthreads();   // B2: tgt_s visible
            if (has_next && tj < BT * KP) {
                int b = tj / KP, k = tj % KP;
                x_s[team][b][k] = emb_s[tgt_s[team * BT + b]][k];
            }
        }
        __syncthreads();       // step barrier: h_s and x_s ready
    }

    if (h_last != nullptr && tj >= 200 && tj < 300) {
        #pragma unroll
        for (int b = 0; b < BT; ++b)
            h_last[(bb0 + b) * HH + i] = h_s[team][b][i];
    }
}

// Final linear + argmax + target_cal.
// block = 256 = 4 slots x 64 lanes (lane = output class d, wave = one (p,b) slot)
__global__ __launch_bounds__(256)
void final_kernel(const float* __restrict__ d1,
                  const float* __restrict__ linW,   // [64,100]
                  const float* __restrict__ linb,   // [64]
                  const int*   __restrict__ tgt,    // [80,1024]
                  float* __restrict__ out0,         // [79*1024,64] logits
                  float* __restrict__ out1,         // [79*1024] target_cal
                  float* __restrict__ out2)         // [79*1024] argmax
{
    __shared__ float WT[HH][64];     // WT[k][d]
    __shared__ __align__(16) float row[4][HH];

    const int tid = threadIdx.x;
    for (int idx = tid; idx < 64 * HH; idx += 256) {
        int d = idx / HH, k = idx % HH;
        WT[k][d] = linW[idx];
    }
    const int s    = tid >> 6;
    const int d    = tid & 63;
    const int slot = blockIdx.x * 4 + s;     // < 79*1024
    const int p    = slot >> 10;
    const int b    = slot & 1023;
    const float* drow = &d1[(long)(p * TB + b) * HH];
    __syncthreads();
    if (d < 50) {
        float2 v = *reinterpret_cast<const float2*>(&drow[2 * d]);
        row[s][2 * d]     = v.x;
        row[s][2 * d + 1] = v.y;
    }
    __syncthreads();

    float acc = linb[d];
    #pragma unroll
    for (int k = 0; k < HH; ++k)
        acc += row[s][k] * WT[k][d];

    out0[(long)slot * 64 + d] = acc;

    // argmax over 64 lanes, first-occurrence tie-break (min index among maxima)
    float mv = acc;
    int   mi = d;
    #pragma unroll
    for (int off = 32; off >= 1; off >>= 1) {
        float ov = __shfl_xor(mv, off, 64);
        int   oi = __shfl_xor(mi, off, 64);
        if (ov > mv || (ov == mv && oi < mi)) { mv = ov; mi = oi; }
    }
    if (d == 0) out2[slot] = (float)mi;
    if (d == 1) out1[slot] = (float)tgt[(p + 1) * TB + b];
}

extern "C" void kernel_launch(void* const* d_in, const int* in_sizes, int n_in,
                              void* d_out, int out_size, void* d_ws, size_t ws_size,
                              hipStream_t stream)
{
    const float* x      = (const float*)d_in[0];
    const int*   target = (const int*)  d_in[1];
    const float* emb    = (const float*)d_in[2];
    const float* eWih0  = (const float*)d_in[3];
    const float* eWhh0  = (const float*)d_in[4];
    const float* ebih0  = (const float*)d_in[5];
    const float* ebhh0  = (const float*)d_in[6];
    const float* eWih1  = (const float*)d_in[7];
    const float* eWhh1  = (const float*)d_in[8];
    const float* ebih1  = (const float*)d_in[9];
    const float* ebhh1  = (const float*)d_in[10];
    const float* dWih0  = (const float*)d_in[11];
    const float* dWhh0  = (const float*)d_in[12];
    const float* dbih0  = (const float*)d_in[13];
    const float* dbhh0  = (const float*)d_in[14];
    const float* dWih1  = (const float*)d_in[15];
    const float* dWhh1  = (const float*)d_in[16];
    const float* dbih1  = (const float*)d_in[17];
    const float* dbhh1  = (const float*)d_in[18];
    const float* linW   = (const float*)d_in[19];
    const float* linb   = (const float*)d_in[20];

    // workspace layout (floats):
    //  [0, 102400)                       h_enc0
    //  [102400, 204800)                  h_enc1
    //  [204800, 204800+51.2M)            e0 during encoder
    //  same region reused for d0/d1 during decoder (e0 dead by then)
    float* ws     = (float*)d_ws;
    float* h_enc0 = ws;
    float* h_enc1 = ws + 102400;
    float* e0     = ws + 204800;                      // 500*1024*100
    float* d0     = ws + 204800;                      // aliases e0 (dead)
    float* d1_    = ws + 204800 + 80 * 1024 * 100;    // 80*1024*100

    dim3 grid(256), blk(640);   // 2 teams x (300+20) threads, BB=4 per block
    // encoder layer 0: raw x input (K=26), write e0 + h_enc0
    gru_kernel<26,  false, true ><<<grid, blk, 0, stream>>>(
        x, nullptr, nullptr, eWih0, eWhh0, ebih0, ebhh0, nullptr, e0, h_enc0, 500);
    // encoder layer 1: e0 input (K=100), only h_enc1 needed
    gru_kernel<100, false, false><<<grid, blk, 0, stream>>>(
        e0, nullptr, nullptr, eWih1, eWhh1, ebih1, ebhh1, nullptr, nullptr, h_enc1, 500);
    // decoder layer 0: embedding-gather input (K=26), h0 = h_enc0
    gru_kernel<26,  true,  true ><<<grid, blk, 0, stream>>>(
        nullptr, target, emb, dWih0, dWhh0, dbih0, dbhh0, h_enc0, d0, nullptr, 80);
    // decoder layer 1: d0 input (K=100), h0 = h_enc1, write d1
    gru_kernel<100, false, true ><<<grid, blk, 0, stream>>>(
        d0, nullptr, nullptr, dWih1, dWhh1, dbih1, dbhh1, h_enc1, d1_, nullptr, 80);

    float* out0 = (float*)d_out;
    float* out1 = out0 + (long)79 * 1024 * 64;
    float* out2 = out1 + 79 * 1024;
    final_kernel<<<dim3(20224), dim3(256), 0, stream>>>(d1_, linW, linb, target,
                                                        out0, out1, out2);
}

// Round 10
// 3587.968 us; speedup vs baseline: 1.4963x; 1.0012x over previous
//
#include <hip/hip_runtime.h>
#include <math.h>
#include <utility>

#define TB 1024   // batch
#define HH 100    // hidden
#define GG 300    // 3*H gate rows

// ---------------------------------------------------------------------------
// NUMERICS ARE FROZEN — DO NOT TOUCH.
// R1 (__expf), R5 (naive exp2), R6 (1-ulp Cody-Waite expm1) ALL flipped the
// same decoder argmax site (absmax=14). Only the ocml expf/tanhf profile
// (R2/R3/R7/R8/R9) lands on the reference side of a knife-edge logit
// near-tie. The transcendentals AND the per-element GEMV/gate expression DAG
// (values, pairing, order) must stay bit-identical. Perf work value-neutral.
// ---------------------------------------------------------------------------
__device__ __forceinline__ float sigmoidf_(float x) {
    return 1.0f / (1.0f + expf(-x));
}
__device__ __forceinline__ float tanhf_(float x) {
    return tanhf(x);
}

// ---------------------------------------------------------------------------
// R9 post-mortem: VGPR=84 (cap 170) + FETCH 105MB/dispatch: the allocator
// REMATERIALIZES wih from global every time-step (ocml is inlined bitcode —
// no calls; the R7 load-site pin only constrains the pin site). enc0==enc1
// duration shows the kernels are reload/LDS-bound, not FMA-bound.
// R10 fix: pin wih IN THE LOOP each iteration. The SSA chain of asm results
// is non-rematerializable -> wih must stay VGPR-resident across the loop
// (scratch round-trip per step would be costlier; allocator prefers regs).
// asm "" emits ZERO instructions — pure regalloc constraint, value-neutral.
// ---------------------------------------------------------------------------
template<size_t... Is>
__device__ __forceinline__ void ldN(std::index_sequence<Is...>,
                                    float* __restrict__ dst,
                                    const float* __restrict__ src) {
    ((dst[Is] = src[Is]), ...);
}
__device__ __forceinline__ float pin_val(float v) {
    asm volatile("" : "+v"(v));
    return v;
}
template<size_t... Is>
__device__ __forceinline__ void pinN(std::index_sequence<Is...>, float* w) {
    ((w[Is] = pin_val(w[Is])), ...);
}

// acc_i: weights from per-thread registers (wih), x broadcast from LDS.
template<int KK, int BT, int LD>
__device__ __forceinline__ void fma_step(const float* __restrict__ w,
                                         const float (*xs)[LD],
                                         float* __restrict__ acc) {
    #pragma unroll
    for (int b = 0; b < BT; ++b) {
        const float4 xv = *reinterpret_cast<const float4*>(&xs[b][KK]);
        acc[b] += w[KK]     * xv.x + w[KK + 1] * xv.y
                + w[KK + 2] * xv.z + w[KK + 3] * xv.w;
    }
}
template<int BT, int LD, size_t... Is>
__device__ __forceinline__ void gemv4(std::index_sequence<Is...>,
                                      const float* __restrict__ w,
                                      const float (*xs)[LD],
                                      float* __restrict__ acc) {
    (fma_step<(int)(Is * 4), BT, LD>(w, xs, acc), ...);
}

// acc_h: weights from LDS k-packed [grp][row][4], h broadcast from LDS.
// Pairing/order identical to fma_step: wv.x==w[4g+0] pairs hv.x==h[4g+0], ...
template<int GRP, int BT>
__device__ __forceinline__ void fma_lds_step(const float* __restrict__ wl,
                                             int row,
                                             const float (*hs)[HH],
                                             float* __restrict__ acc) {
    const float4 wv = *reinterpret_cast<const float4*>(wl + (GRP * GG + row) * 4);
    #pragma unroll
    for (int b = 0; b < BT; ++b) {
        const float4 hv = *reinterpret_cast<const float4*>(&hs[b][GRP * 4]);
        acc[b] += wv.x * hv.x + wv.y * hv.y + wv.z * hv.z + wv.w * hv.w;
    }
}
template<int BT, size_t... Is>
__device__ __forceinline__ void gemv_lds(std::index_sequence<Is...>,
                                         const float* __restrict__ wl, int row,
                                         const float (*hs)[HH],
                                         float* __restrict__ acc) {
    (fma_lds_step<(int)Is, BT>(wl, row, hs, acc), ...);
}

// Persistent GRU layer kernel. grid=256 blocks, block=640 threads (10 waves).
// team = tid/320 (2 teams of 300 gate-rows + 20 pad), each team owns BT=2
// batch elements; whh shared in LDS. 10 waves/CU -> 3/3/2/2 per SIMD.
template<int K, bool EMB, bool WRITE_SEQ>
__global__ __launch_bounds__(640, 3)
void gru_kernel(const float* __restrict__ xin,   // [T,B,K] (if !EMB)
                const int*   __restrict__ tgt,   // [T,B]   (if EMB)
                const float* __restrict__ emb,   // [64,26] (if EMB)
                const float* __restrict__ Wih,   // [300,K]
                const float* __restrict__ Whh,   // [300,100]
                const float* __restrict__ bih,
                const float* __restrict__ bhh,
                const float* __restrict__ h_init,// [B,100] or null -> zeros
                float* __restrict__ seq_out,     // [T,B,100] (if WRITE_SEQ)
                float* __restrict__ h_last,      // [B,100] or null
                int T)
{
    constexpr int KP = (K + 3) & ~3;   // 28 or 100
    constexpr int BT = 2;              // batch per team
    constexpr int NT = 2;              // teams
    static_assert(KP % 4 == 0, "");

    const int tid  = threadIdx.x;
    const int team = tid / 320;
    const int tj   = tid % 320;        // row index within team (0..319)
    const int bb0  = blockIdx.x * (BT * NT) + team * BT;
    const int g    = tj / 100;
    const int i    = tj % 100;

    __shared__ __align__(16) float whh_l[(HH / 4) * GG * 4];  // 120000 B
    __shared__ __align__(16) float h_s[NT][BT][HH];
    __shared__ __align__(16) float x_s[NT][BT][KP];
    __shared__ float r_s[NT][BT][HH];
    __shared__ float z_s[NT][BT][HH];
    __shared__ float emb_s[EMB ? 64 : 1][EMB ? 28 : 4];
    __shared__ int   tgt_s[NT * BT];

    // ---- wih row into registers (one-time, unconditional w/ clamped row) ----
    const int jj = (tj < GG) ? tj : 0;
    float wih[KP];
    ldN(std::make_index_sequence<K>{}, wih, Wih + (long)jj * K);
    #pragma unroll
    for (int k = K; k < KP; ++k) wih[k] = 0.f;
    float bi = bih[jj];
    float bh = bhh[jj];

    // ---- stage whh into LDS, k-packed: whh_l[(k/4)*GG + row][k%4] ----
    for (int idx = tid; idx < GG * HH; idx += 640) {
        int row = idx / HH, k = idx % HH;
        whh_l[((k >> 2) * GG + row) * 4 + (k & 3)] = Whh[row * HH + k];
    }

    // ---- init h (per team) ----
    for (int idx = tj; idx < BT * HH; idx += 320) {
        int b = idx / HH, k = idx % HH;
        h_s[team][b][k] = h_init ? h_init[(bb0 + b) * HH + k] : 0.f;
    }
    // ---- init x_s for t=0 ----
    if constexpr (EMB) {
        for (int idx = tid; idx < 64 * 28; idx += 640) {
            int d = idx / 28, k = idx % 28;
            emb_s[d][k] = (k < 26) ? emb[d * 26 + k] : 0.f;
        }
        __syncthreads();
        for (int idx = tj; idx < BT * KP; idx += 320) {
            int b = idx / KP, k = idx % KP;
            int t0 = tgt[bb0 + b];
            x_s[team][b][k] = emb_s[t0][k];    // pads are 0 via emb_s
        }
    } else {
        for (int idx = tj; idx < BT * KP; idx += 320) {
            int b = idx / KP, k = idx % KP;
            x_s[team][b][k] = (k < K) ? xin[(bb0 + b) * K + k] : 0.f;
        }
    }
    __syncthreads();   // whh_l, h_s, x_s ready

    // ---- time loop ----
    for (int t = 0; t < T; ++t) {
        // IN-LOOP PIN: non-rematerializable SSA chain -> wih stays resident.
        pinN(std::make_index_sequence<KP>{}, wih);
        bi = pin_val(bi);
        bh = pin_val(bh);

        const bool has_next = (t + 1 < T);

        // prefetch next step's input into regs (hidden under FMA loop)
        float px = 0.f;
        int   ptg = 0;
        if constexpr (!EMB) {
            if (has_next && !(tj >= 200 && tj < 300)) {
                int stid = (tj < 200) ? tj : tj - 100;   // 0..219
                if (stid < BT * K)
                    px = xin[((t + 1) * TB + bb0 + stid / K) * K + stid % K];
            }
        } else {
            if (has_next && tj < BT) ptg = tgt[(t + 1) * TB + bb0 + tj];
        }

        // main GEMV: acc_i = Wih[j,:].x + bi ; acc_h = Whh[j,:].h + bh
        float acc_i[BT], acc_h[BT];
        #pragma unroll
        for (int b = 0; b < BT; ++b) { acc_i[b] = bi; acc_h[b] = bh; }

        gemv4<BT, KP>(std::make_index_sequence<KP / 4>{}, wih, x_s[team], acc_i);
        gemv_lds<BT>(std::make_index_sequence<HH / 4>{}, whh_l, jj, h_s[team], acc_h);

        // r / z gates -> LDS
        if (tj < 200) {
            #pragma unroll
            for (int b = 0; b < BT; ++b) {
                float v = sigmoidf_(acc_i[b] + acc_h[b]);
                if (g == 0) r_s[team][b][i] = v;
                else        z_s[team][b][i] = v;
            }
        }
        __syncthreads();   // B1: gates visible

        if (tj >= 200 && tj < 300) {
            // n gate + state update (100 threads per team)
            #pragma unroll
            for (int b = 0; b < BT; ++b) {
                float n  = tanhf_(acc_i[b] + r_s[team][b][i] * acc_h[b]);
                float z  = z_s[team][b][i];
                float hn = (1.f - z) * n + z * h_s[team][b][i];
                h_s[team][b][i] = hn;
                if (WRITE_SEQ)
                    seq_out[((long)t * TB + bb0 + b) * HH + i] = hn;
            }
        } else if constexpr (!EMB) {
            if (has_next) {
                int stid = (tj < 200) ? tj : tj - 100;
                if (stid < BT * K) x_s[team][stid / K][stid % K] = px;
            }
        }
        if constexpr (EMB) {
            if (has_next && tj < BT) tgt_s[team * BT + tj] = ptg;
            __syncthreads();   // B2: tgt_s visible
            if (has_next && tj < BT * KP) {
                int b = tj / KP, k = tj % KP;
                x_s[team][b][k] = emb_s[tgt_s[team * BT + b]][k];
            }
        }
        __syncthreads();       // step barrier: h_s and x_s ready
    }

    if (h_last != nullptr && tj >= 200 && tj < 300) {
        #pragma unroll
        for (int b = 0; b < BT; ++b)
            h_last[(bb0 + b) * HH + i] = h_s[team][b][i];
    }
}

// Final linear + argmax + target_cal.
// block = 256 = 4 slots x 64 lanes (lane = output class d, wave = one (p,b) slot)
__global__ __launch_bounds__(256)
void final_kernel(const float* __restrict__ d1,
                  const float* __restrict__ linW,   // [64,100]
                  const float* __restrict__ linb,   // [64]
                  const int*   __restrict__ tgt,    // [80,1024]
                  float* __restrict__ out0,         // [79*1024,64] logits
                  float* __restrict__ out1,         // [79*1024] target_cal
                  float* __restrict__ out2)         // [79*1024] argmax
{
    __shared__ float WT[HH][64];     // WT[k][d]
    __shared__ __align__(16) float row[4][HH];

    const int tid = threadIdx.x;
    for (int idx = tid; idx < 64 * HH; idx += 256) {
        int d = idx / HH, k = idx % HH;
        WT[k][d] = linW[idx];
    }
    const int s    = tid >> 6;
    const int d    = tid & 63;
    const int slot = blockIdx.x * 4 + s;     // < 79*1024
    const int p    = slot >> 10;
    const int b    = slot & 1023;
    const float* drow = &d1[(long)(p * TB + b) * HH];
    __syncthreads();
    if (d < 50) {
        float2 v = *reinterpret_cast<const float2*>(&drow[2 * d]);
        row[s][2 * d]     = v.x;
        row[s][2 * d + 1] = v.y;
    }
    __syncthreads();

    float acc = linb[d];
    #pragma unroll
    for (int k = 0; k < HH; ++k)
        acc += row[s][k] * WT[k][d];

    out0[(long)slot * 64 + d] = acc;

    // argmax over 64 lanes, first-occurrence tie-break (min index among maxima)
    float mv = acc;
    int   mi = d;
    #pragma unroll
    for (int off = 32; off >= 1; off >>= 1) {
        float ov = __shfl_xor(mv, off, 64);
        int   oi = __shfl_xor(mi, off, 64);
        if (ov > mv || (ov == mv && oi < mi)) { mv = ov; mi = oi; }
    }
    if (d == 0) out2[slot] = (float)mi;
    if (d == 1) out1[slot] = (float)tgt[(p + 1) * TB + b];
}

extern "C" void kernel_launch(void* const* d_in, const int* in_sizes, int n_in,
                              void* d_out, int out_size, void* d_ws, size_t ws_size,
                              hipStream_t stream)
{
    const float* x      = (const float*)d_in[0];
    const int*   target = (const int*)  d_in[1];
    const float* emb    = (const float*)d_in[2];
    const float* eWih0  = (const float*)d_in[3];
    const float* eWhh0  = (const float*)d_in[4];
    const float* ebih0  = (const float*)d_in[5];
    const float* ebhh0  = (const float*)d_in[6];
    const float* eWih1  = (const float*)d_in[7];
    const float* eWhh1  = (const float*)d_in[8];
    const float* ebih1  = (const float*)d_in[9];
    const float* ebhh1  = (const float*)d_in[10];
    const float* dWih0  = (const float*)d_in[11];
    const float* dWhh0  = (const float*)d_in[12];
    const float* dbih0  = (const float*)d_in[13];
    const float* dbhh0  = (const float*)d_in[14];
    const float* dWih1  = (const float*)d_in[15];
    const float* dWhh1  = (const float*)d_in[16];
    const float* dbih1  = (const float*)d_in[17];
    const float* dbhh1  = (const float*)d_in[18];
    const float* linW   = (const float*)d_in[19];
    const float* linb   = (const float*)d_in[20];

    // workspace layout (floats):
    //  [0, 102400)                       h_enc0
    //  [102400, 204800)                  h_enc1
    //  [204800, 204800+51.2M)            e0 during encoder
    //  same region reused for d0/d1 during decoder (e0 dead by then)
    float* ws     = (float*)d_ws;
    float* h_enc0 = ws;
    float* h_enc1 = ws + 102400;
    float* e0     = ws + 204800;                      // 500*1024*100
    float* d0     = ws + 204800;                      // aliases e0 (dead)
    float* d1_    = ws + 204800 + 80 * 1024 * 100;    // 80*1024*100

    dim3 grid(256), blk(640);   // 2 teams x (300+20) threads, BB=4 per block
    // encoder layer 0: raw x input (K=26), write e0 + h_enc0
    gru_kernel<26,  false, true ><<<grid, blk, 0, stream>>>(
        x, nullptr, nullptr, eWih0, eWhh0, ebih0, ebhh0, nullptr, e0, h_enc0, 500);
    // encoder layer 1: e0 input (K=100), only h_enc1 needed
    gru_kernel<100, false, false><<<grid, blk, 0, stream>>>(
        e0, nullptr, nullptr, eWih1, eWhh1, ebih1, ebhh1, nullptr, nullptr, h_enc1, 500);
    // decoder layer 0: embedding-gather input (K=26), h0 = h_enc0
    gru_kernel<26,  true,  true ><<<grid, blk, 0, stream>>>(
        nullptr, target, emb, dWih0, dWhh0, dbih0, dbhh0, h_enc0, d0, nullptr, 80);
    // decoder layer 1: d0 input (K=100), h0 = h_enc1, write d1
    gru_kernel<100, false, true ><<<grid, blk, 0, stream>>>(
        d0, nullptr, nullptr, dWih1, dWhh1, dbih1, dbhh1, h_enc1, d1_, nullptr, 80);

    float* out0 = (float*)d_out;
    float* out1 = out0 + (long)79 * 1024 * 64;
    float* out2 = out1 + 79 * 1024;
    final_kernel<<<dim3(20224), dim3(256), 0, stream>>>(d1_, linW, linb, target,
                                                        out0, out1, out2);
}